// Round 1
// baseline (523.429 us; speedup 1.0000x reference)
//
#include <hip/hip_runtime.h>

#define IN_CH   128
#define HIDDEN  256
#define N_GRAPHS 64
#define GN 64  // nodes per gemm block

__global__ void k_deg(const int* __restrict__ dst, int* __restrict__ deg, int e) {
  int i = blockIdx.x * blockDim.x + threadIdx.x;
  if (i < e) atomicAdd(&deg[dst[i]], 1);
}

__global__ void k_cnt(const int* __restrict__ batch, int* __restrict__ cnt, int n) {
  int i = blockIdx.x * blockDim.x + threadIdx.x;
  if (i < n) atomicAdd(&cnt[batch[i]], 1);
}

__global__ void k_dinv(const int* __restrict__ deg, float* __restrict__ dinv, int n) {
  int i = blockIdx.x * blockDim.x + threadIdx.x;
  if (i < n) dinv[i] = 1.0f / sqrtf((float)(deg[i] + 1));  // +1 self-loop
}

__global__ __launch_bounds__(1024) void k_scan1(const int* __restrict__ deg,
    int* __restrict__ offs, int* __restrict__ bsum, int n) {
  __shared__ int sm[1024];
  int t = threadIdx.x;
  int i = blockIdx.x * 1024 + t;
  int v = (i < n) ? deg[i] : 0;
  sm[t] = v;
  __syncthreads();
  for (int d = 1; d < 1024; d <<= 1) {
    int add = (t >= d) ? sm[t - d] : 0;
    __syncthreads();
    sm[t] += add;
    __syncthreads();
  }
  if (i < n) offs[i] = sm[t] - v;  // exclusive
  if (t == 1023) bsum[blockIdx.x] = sm[1023];
}

__global__ void k_scan2(const int* __restrict__ bsum, int* __restrict__ bofs, int nb) {
  if (threadIdx.x == 0 && blockIdx.x == 0) {
    int run = 0;
    for (int b = 0; b < nb; ++b) { bofs[b] = run; run += bsum[b]; }
  }
}

__global__ void k_scan3(int* __restrict__ offs, int* __restrict__ cursor,
                        const int* __restrict__ bofs, int n) {
  int i = blockIdx.x * blockDim.x + threadIdx.x;
  if (i < n) {
    int o = offs[i] + bofs[i >> 10];
    offs[i] = o;
    cursor[i] = o;
  }
}

__global__ void k_scatter(const int* __restrict__ src, const int* __restrict__ dst,
                          int* __restrict__ cursor, int* __restrict__ csr, int e) {
  int i = blockIdx.x * blockDim.x + threadIdx.x;
  if (i < e) {
    int d = dst[i];
    int pos = atomicAdd(&cursor[d], 1);
    csr[pos] = src[i];
  }
}

// One wave per node: y[n][0:128] = dinv[n] * ( sum_{s in N(n)} x[s]*dinv[s] + x[n]*dinv[n] )
__global__ __launch_bounds__(256) void k_agg(const float* __restrict__ x,
    const int* __restrict__ csr, const int* __restrict__ offs,
    const int* __restrict__ degc, const float* __restrict__ dinv,
    float* __restrict__ y, int n) {
  int gw = (blockIdx.x * 256 + threadIdx.x) >> 6;
  int lane = threadIdx.x & 63;
  if (gw >= n) return;
  int o = offs[gw], c = degc[gw];
  float ax = 0.f, ay = 0.f;
  int j = 0;
  for (; j + 1 < c; j += 2) {
    int s0 = csr[o + j], s1 = csr[o + j + 1];
    float w0 = dinv[s0], w1_ = dinv[s1];
    float2 v0 = *reinterpret_cast<const float2*>(&x[(size_t)s0 * IN_CH + lane * 2]);
    float2 v1 = *reinterpret_cast<const float2*>(&x[(size_t)s1 * IN_CH + lane * 2]);
    ax += v0.x * w0 + v1.x * w1_;
    ay += v0.y * w0 + v1.y * w1_;
  }
  if (j < c) {
    int s0 = csr[o + j];
    float w0 = dinv[s0];
    float2 v0 = *reinterpret_cast<const float2*>(&x[(size_t)s0 * IN_CH + lane * 2]);
    ax += v0.x * w0;
    ay += v0.y * w0;
  }
  float dn = dinv[gw];
  float2 xs = *reinterpret_cast<const float2*>(&x[(size_t)gw * IN_CH + lane * 2]);
  ax = (ax + xs.x * dn) * dn;
  ay = (ay + xs.y * dn) * dn;
  *reinterpret_cast<float2*>(&y[(size_t)gw * IN_CH + lane * 2]) = float2{ax, ay};
}

// h[n] = relu(y[n] @ w1 + b1), 64 nodes/block, 256 threads.
// thread: cg = t&31 owns channels {cg*4..cg*4+3} and {128+cg*4..}, ng = t>>5 owns 8 nodes.
__global__ __launch_bounds__(256) void k_gemm1(const float* __restrict__ y,
    const float* __restrict__ w1, const float* __restrict__ b1,
    float* __restrict__ h, int n) {
  __shared__ float ylds[GN * 128];   // 32 KB
  __shared__ float wlds[16 * 256];   // 16 KB
  int t = threadIdx.x;
  int node0 = blockIdx.x * GN;
  {
    const float4* ys = reinterpret_cast<const float4*>(y);
    float4* yd = reinterpret_cast<float4*>(ylds);
    int base4 = node0 * 32, tot4 = n * 32;
#pragma unroll
    for (int i = 0; i < (GN * 32) / 256; ++i) {
      int idx = t + i * 256;
      int g = base4 + idx;
      float4 v = {0.f, 0.f, 0.f, 0.f};
      if (g < tot4) v = ys[g];
      yd[idx] = v;
    }
  }
  int cg = t & 31, ng = t >> 5;
  float acc[8][8];
#pragma unroll
  for (int m = 0; m < 8; ++m)
#pragma unroll
    for (int c = 0; c < 8; ++c) acc[m][c] = 0.f;

  for (int k0 = 0; k0 < 128; k0 += 16) {
    __syncthreads();
    {
      const float4* ws4 = reinterpret_cast<const float4*>(w1 + k0 * 256);
      float4* wd = reinterpret_cast<float4*>(wlds);
#pragma unroll
      for (int i = 0; i < 4; ++i) wd[t + i * 256] = ws4[t + i * 256];
    }
    __syncthreads();
#pragma unroll
    for (int kk = 0; kk < 16; kk += 4) {
      float4 wv0[4], wv1[4];
#pragma unroll
      for (int u = 0; u < 4; ++u) {
        const float* wr = &wlds[(kk + u) * 256 + cg * 4];
        wv0[u] = *reinterpret_cast<const float4*>(wr);
        wv1[u] = *reinterpret_cast<const float4*>(wr + 128);
      }
#pragma unroll
      for (int m = 0; m < 8; ++m) {
        float4 yv = *reinterpret_cast<const float4*>(&ylds[(ng * 8 + m) * 128 + k0 + kk]);
        float ya[4] = {yv.x, yv.y, yv.z, yv.w};
#pragma unroll
        for (int u = 0; u < 4; ++u) {
          acc[m][0] += ya[u] * wv0[u].x;
          acc[m][1] += ya[u] * wv0[u].y;
          acc[m][2] += ya[u] * wv0[u].z;
          acc[m][3] += ya[u] * wv0[u].w;
          acc[m][4] += ya[u] * wv1[u].x;
          acc[m][5] += ya[u] * wv1[u].y;
          acc[m][6] += ya[u] * wv1[u].z;
          acc[m][7] += ya[u] * wv1[u].w;
        }
      }
    }
  }
  float b0[4], b4[4];
#pragma unroll
  for (int u = 0; u < 4; ++u) { b0[u] = b1[cg * 4 + u]; b4[u] = b1[128 + cg * 4 + u]; }
#pragma unroll
  for (int m = 0; m < 8; ++m) {
    int node = node0 + ng * 8 + m;
    if (node < n) {
      float4 o0, o1;
      o0.x = fmaxf(acc[m][0] + b0[0], 0.f);
      o0.y = fmaxf(acc[m][1] + b0[1], 0.f);
      o0.z = fmaxf(acc[m][2] + b0[2], 0.f);
      o0.w = fmaxf(acc[m][3] + b0[3], 0.f);
      o1.x = fmaxf(acc[m][4] + b4[0], 0.f);
      o1.y = fmaxf(acc[m][5] + b4[1], 0.f);
      o1.z = fmaxf(acc[m][6] + b4[2], 0.f);
      o1.w = fmaxf(acc[m][7] + b4[3], 0.f);
      *reinterpret_cast<float4*>(&h[(size_t)node * 256 + cg * 4]) = o0;
      *reinterpret_cast<float4*>(&h[(size_t)node * 256 + 128 + cg * 4]) = o1;
    }
  }
}

// batch is sorted: run-length accumulate, flush per graph-change.
__global__ __launch_bounds__(256) void k_pool(const float* __restrict__ h,
    const int* __restrict__ batch, float* __restrict__ pooled, int n) {
  int per = (n + gridDim.x - 1) / gridDim.x;
  int s = blockIdx.x * per;
  int e_ = min(n, s + per);
  if (s >= e_) return;
  int ch = threadIdx.x;
  float acc = 0.f;
  int g = batch[s];
  for (int i = s; i < e_; ++i) {
    int gi = batch[i];
    if (gi != g) {
      atomicAdd(&pooled[g * HIDDEN + ch], acc);
      acc = 0.f;
      g = gi;
    }
    acc += h[(size_t)i * HIDDEN + ch];
  }
  atomicAdd(&pooled[g * HIDDEN + ch], acc);
}

// One block per graph: mean, z = relu(p@w2+b2), out = z@w3+b3
__global__ __launch_bounds__(256) void k_head(const float* __restrict__ pooled,
    const int* __restrict__ cnt, const float* __restrict__ w2,
    const float* __restrict__ b2, const float* __restrict__ w3,
    const float* __restrict__ b3, float* __restrict__ out) {
  __shared__ float p[256];
  __shared__ float red[4];
  int g = blockIdx.x, t = threadIdx.x;
  float c = (float)max(cnt[g], 1);
  p[t] = pooled[g * HIDDEN + t] / c;
  __syncthreads();
  float a = 0.f;
  for (int k = 0; k < 256; ++k) a += p[k] * w2[k * 256 + t];
  a += b2[t];
  a = fmaxf(a, 0.f);
  float part = a * w3[t];
  for (int off = 32; off > 0; off >>= 1) part += __shfl_down(part, off, 64);
  if ((t & 63) == 0) red[t >> 6] = part;
  __syncthreads();
  if (t == 0) out[g] = red[0] + red[1] + red[2] + red[3] + b3[0];
}

extern "C" void kernel_launch(void* const* d_in, const int* in_sizes, int n_in,
                              void* d_out, int out_size, void* d_ws, size_t ws_size,
                              hipStream_t stream) {
  const float* x    = (const float*)d_in[0];
  const int*   ei   = (const int*)d_in[1];
  const int*   batch= (const int*)d_in[2];
  const float* w1   = (const float*)d_in[3];
  const float* b1   = (const float*)d_in[4];
  const float* w2   = (const float*)d_in[5];
  const float* b2   = (const float*)d_in[6];
  const float* w3   = (const float*)d_in[7];
  const float* b3   = (const float*)d_in[8];
  float* out = (float*)d_out;

  int N = in_sizes[2];
  int E = in_sizes[1] / 2;
  const int* esrc = ei;
  const int* edst = ei + E;

  int* W = (int*)d_ws;
  int*   deg_i  = W;
  int*   offs   = W + N;
  int*   cursor = W + 2 * N;
  float* dinv   = (float*)(W + 3 * N);
  int*   bsum   = W + 4 * N;
  int*   bofs   = bsum + 64;
  int*   cnt    = bofs + 64;
  float* pooled = (float*)(cnt + 64);
  int*   csr    = (int*)(pooled + N_GRAPHS * HIDDEN);
  float* yb     = (float*)(csr + E);
  float* hb     = yb + (size_t)N * IN_CH;

  hipMemsetAsync(deg_i, 0, (size_t)N * sizeof(int), stream);
  hipMemsetAsync(cnt, 0, (size_t)(64 + N_GRAPHS * HIDDEN) * sizeof(int), stream);

  const int tb = 256;
  k_deg<<<(E + tb - 1) / tb, tb, 0, stream>>>(edst, deg_i, E);
  k_cnt<<<(N + tb - 1) / tb, tb, 0, stream>>>(batch, cnt, N);
  k_dinv<<<(N + tb - 1) / tb, tb, 0, stream>>>(deg_i, dinv, N);
  int nb = (N + 1023) / 1024;
  k_scan1<<<nb, 1024, 0, stream>>>(deg_i, offs, bsum, N);
  k_scan2<<<1, 64, 0, stream>>>(bsum, bofs, nb);
  k_scan3<<<(N + tb - 1) / tb, tb, 0, stream>>>(offs, cursor, bofs, N);
  k_scatter<<<(E + tb - 1) / tb, tb, 0, stream>>>(esrc, edst, cursor, csr, E);
  k_agg<<<(N * 64 + tb - 1) / tb, tb, 0, stream>>>(x, csr, offs, deg_i, dinv, yb, N);
  k_gemm1<<<(N + GN - 1) / GN, 256, 0, stream>>>(yb, w1, b1, hb, N);
  k_pool<<<256, tb, 0, stream>>>(hb, batch, pooled, N);
  k_head<<<N_GRAPHS, 256, 0, stream>>>(pooled, cnt, w2, b2, w3, b3, out);
}

// Round 2
// 295.242 us; speedup vs baseline: 1.7729x; 1.7729x over previous
//
#include <hip/hip_runtime.h>

#define IN_CH   128
#define HIDDEN  256
#define N_GRAPHS 64
#define GN 64  // nodes per gemm block

__global__ void k_deg(const int* __restrict__ dst, int* __restrict__ deg, int e) {
  int i = blockIdx.x * blockDim.x + threadIdx.x;
  if (i < e) atomicAdd(&deg[dst[i]], 1);
}

// batch is sorted: cnt[g] = lower_bound(g+1) - lower_bound(g). No atomics.
__global__ void k_cnt_bs(const int* __restrict__ batch, int* __restrict__ cnt, int n) {
  int g = threadIdx.x;
  if (g >= N_GRAPHS) return;
  int lo = 0, hi = n;
  while (lo < hi) { int mid = (lo + hi) >> 1; if (batch[mid] < g) lo = mid + 1; else hi = mid; }
  int a = lo;
  lo = 0; hi = n;
  int g1 = g + 1;
  while (lo < hi) { int mid = (lo + hi) >> 1; if (batch[mid] < g1) lo = mid + 1; else hi = mid; }
  cnt[g] = lo - a;
}

__global__ void k_dinv(const int* __restrict__ deg, float* __restrict__ dinv, int n) {
  int i = blockIdx.x * blockDim.x + threadIdx.x;
  if (i < n) dinv[i] = 1.0f / sqrtf((float)(deg[i] + 1));  // +1 self-loop
}

__global__ __launch_bounds__(1024) void k_scan1(const int* __restrict__ deg,
    int* __restrict__ offs, int* __restrict__ bsum, int n) {
  __shared__ int sm[1024];
  int t = threadIdx.x;
  int i = blockIdx.x * 1024 + t;
  int v = (i < n) ? deg[i] : 0;
  sm[t] = v;
  __syncthreads();
  for (int d = 1; d < 1024; d <<= 1) {
    int add = (t >= d) ? sm[t - d] : 0;
    __syncthreads();
    sm[t] += add;
    __syncthreads();
  }
  if (i < n) offs[i] = sm[t] - v;  // exclusive
  if (t == 1023) bsum[blockIdx.x] = sm[1023];
}

__global__ void k_scan2(const int* __restrict__ bsum, int* __restrict__ bofs, int nb) {
  if (threadIdx.x == 0 && blockIdx.x == 0) {
    int run = 0;
    for (int b = 0; b < nb; ++b) { bofs[b] = run; run += bsum[b]; }
  }
}

__global__ void k_scan3(int* __restrict__ offs, int* __restrict__ cursor,
                        const int* __restrict__ bofs, int n) {
  int i = blockIdx.x * blockDim.x + threadIdx.x;
  if (i < n) {
    int o = offs[i] + bofs[i >> 10];
    offs[i] = o;
    cursor[i] = o;
  }
}

__global__ void k_scatter(const int* __restrict__ src, const int* __restrict__ dst,
                          int* __restrict__ cursor, int* __restrict__ csr, int e) {
  int i = blockIdx.x * blockDim.x + threadIdx.x;
  if (i < e) {
    int d = dst[i];
    int pos = atomicAdd(&cursor[d], 1);
    csr[pos] = src[i];
  }
}

// One wave per node: y[n][0:128] = dinv[n] * ( sum_{s in N(n)} x[s]*dinv[s] + x[n]*dinv[n] )
__global__ __launch_bounds__(256) void k_agg(const float* __restrict__ x,
    const int* __restrict__ csr, const int* __restrict__ offs,
    const int* __restrict__ degc, const float* __restrict__ dinv,
    float* __restrict__ y, int n) {
  int gw = (blockIdx.x * 256 + threadIdx.x) >> 6;
  int lane = threadIdx.x & 63;
  if (gw >= n) return;
  int o = offs[gw], c = degc[gw];
  float ax = 0.f, ay = 0.f;
  int j = 0;
  for (; j + 1 < c; j += 2) {
    int s0 = csr[o + j], s1 = csr[o + j + 1];
    float w0 = dinv[s0], w1_ = dinv[s1];
    float2 v0 = *reinterpret_cast<const float2*>(&x[(size_t)s0 * IN_CH + lane * 2]);
    float2 v1 = *reinterpret_cast<const float2*>(&x[(size_t)s1 * IN_CH + lane * 2]);
    ax += v0.x * w0 + v1.x * w1_;
    ay += v0.y * w0 + v1.y * w1_;
  }
  if (j < c) {
    int s0 = csr[o + j];
    float w0 = dinv[s0];
    float2 v0 = *reinterpret_cast<const float2*>(&x[(size_t)s0 * IN_CH + lane * 2]);
    ax += v0.x * w0;
    ay += v0.y * w0;
  }
  float dn = dinv[gw];
  float2 xs = *reinterpret_cast<const float2*>(&x[(size_t)gw * IN_CH + lane * 2]);
  ax = (ax + xs.x * dn) * dn;
  ay = (ay + xs.y * dn) * dn;
  *reinterpret_cast<float2*>(&y[(size_t)gw * IN_CH + lane * 2]) = float2{ax, ay};
}

// h[n] = relu(y[n] @ w1 + b1), 64 nodes/block, 256 threads.
__global__ __launch_bounds__(256) void k_gemm1(const float* __restrict__ y,
    const float* __restrict__ w1, const float* __restrict__ b1,
    float* __restrict__ h, int n) {
  __shared__ float ylds[GN * 128];   // 32 KB
  __shared__ float wlds[16 * 256];   // 16 KB
  int t = threadIdx.x;
  int node0 = blockIdx.x * GN;
  {
    const float4* ys = reinterpret_cast<const float4*>(y);
    float4* yd = reinterpret_cast<float4*>(ylds);
    int base4 = node0 * 32, tot4 = n * 32;
#pragma unroll
    for (int i = 0; i < (GN * 32) / 256; ++i) {
      int idx = t + i * 256;
      int g = base4 + idx;
      float4 v = {0.f, 0.f, 0.f, 0.f};
      if (g < tot4) v = ys[g];
      yd[idx] = v;
    }
  }
  int cg = t & 31, ng = t >> 5;
  float acc[8][8];
#pragma unroll
  for (int m = 0; m < 8; ++m)
#pragma unroll
    for (int c = 0; c < 8; ++c) acc[m][c] = 0.f;

  for (int k0 = 0; k0 < 128; k0 += 16) {
    __syncthreads();
    {
      const float4* ws4 = reinterpret_cast<const float4*>(w1 + k0 * 256);
      float4* wd = reinterpret_cast<float4*>(wlds);
#pragma unroll
      for (int i = 0; i < 4; ++i) wd[t + i * 256] = ws4[t + i * 256];
    }
    __syncthreads();
#pragma unroll
    for (int kk = 0; kk < 16; kk += 4) {
      float4 wv0[4], wv1[4];
#pragma unroll
      for (int u = 0; u < 4; ++u) {
        const float* wr = &wlds[(kk + u) * 256 + cg * 4];
        wv0[u] = *reinterpret_cast<const float4*>(wr);
        wv1[u] = *reinterpret_cast<const float4*>(wr + 128);
      }
#pragma unroll
      for (int m = 0; m < 8; ++m) {
        float4 yv = *reinterpret_cast<const float4*>(&ylds[(ng * 8 + m) * 128 + k0 + kk]);
        float ya[4] = {yv.x, yv.y, yv.z, yv.w};
#pragma unroll
        for (int u = 0; u < 4; ++u) {
          acc[m][0] += ya[u] * wv0[u].x;
          acc[m][1] += ya[u] * wv0[u].y;
          acc[m][2] += ya[u] * wv0[u].z;
          acc[m][3] += ya[u] * wv0[u].w;
          acc[m][4] += ya[u] * wv1[u].x;
          acc[m][5] += ya[u] * wv1[u].y;
          acc[m][6] += ya[u] * wv1[u].z;
          acc[m][7] += ya[u] * wv1[u].w;
        }
      }
    }
  }
  float b0[4], b4[4];
#pragma unroll
  for (int u = 0; u < 4; ++u) { b0[u] = b1[cg * 4 + u]; b4[u] = b1[128 + cg * 4 + u]; }
#pragma unroll
  for (int m = 0; m < 8; ++m) {
    int node = node0 + ng * 8 + m;
    if (node < n) {
      float4 o0, o1;
      o0.x = fmaxf(acc[m][0] + b0[0], 0.f);
      o0.y = fmaxf(acc[m][1] + b0[1], 0.f);
      o0.z = fmaxf(acc[m][2] + b0[2], 0.f);
      o0.w = fmaxf(acc[m][3] + b0[3], 0.f);
      o1.x = fmaxf(acc[m][4] + b4[0], 0.f);
      o1.y = fmaxf(acc[m][5] + b4[1], 0.f);
      o1.z = fmaxf(acc[m][6] + b4[2], 0.f);
      o1.w = fmaxf(acc[m][7] + b4[3], 0.f);
      *reinterpret_cast<float4*>(&h[(size_t)node * 256 + cg * 4]) = o0;
      *reinterpret_cast<float4*>(&h[(size_t)node * 256 + 128 + cg * 4]) = o1;
    }
  }
}

// batch is sorted: run-length accumulate, flush per graph-change.
__global__ __launch_bounds__(256) void k_pool(const float* __restrict__ h,
    const int* __restrict__ batch, float* __restrict__ pooled, int n) {
  int per = (n + gridDim.x - 1) / gridDim.x;
  int s = blockIdx.x * per;
  int e_ = min(n, s + per);
  if (s >= e_) return;
  int ch = threadIdx.x;
  float acc = 0.f;
  int g = batch[s];
  for (int i = s; i < e_; ++i) {
    int gi = batch[i];
    if (gi != g) {
      atomicAdd(&pooled[g * HIDDEN + ch], acc);
      acc = 0.f;
      g = gi;
    }
    acc += h[(size_t)i * HIDDEN + ch];
  }
  atomicAdd(&pooled[g * HIDDEN + ch], acc);
}

// One block per graph: mean, z = relu(p@w2+b2), out = z@w3+b3
__global__ __launch_bounds__(256) void k_head(const float* __restrict__ pooled,
    const int* __restrict__ cnt, const float* __restrict__ w2,
    const float* __restrict__ b2, const float* __restrict__ w3,
    const float* __restrict__ b3, float* __restrict__ out) {
  __shared__ float p[256];
  __shared__ float red[4];
  int g = blockIdx.x, t = threadIdx.x;
  float c = (float)max(cnt[g], 1);
  p[t] = pooled[g * HIDDEN + t] / c;
  __syncthreads();
  float a = 0.f;
  for (int k = 0; k < 256; ++k) a += p[k] * w2[k * 256 + t];
  a += b2[t];
  a = fmaxf(a, 0.f);
  float part = a * w3[t];
  for (int off = 32; off > 0; off >>= 1) part += __shfl_down(part, off, 64);
  if ((t & 63) == 0) red[t >> 6] = part;
  __syncthreads();
  if (t == 0) out[g] = red[0] + red[1] + red[2] + red[3] + b3[0];
}

extern "C" void kernel_launch(void* const* d_in, const int* in_sizes, int n_in,
                              void* d_out, int out_size, void* d_ws, size_t ws_size,
                              hipStream_t stream) {
  const float* x    = (const float*)d_in[0];
  const int*   ei   = (const int*)d_in[1];
  const int*   batch= (const int*)d_in[2];
  const float* w1   = (const float*)d_in[3];
  const float* b1   = (const float*)d_in[4];
  const float* w2   = (const float*)d_in[5];
  const float* b2   = (const float*)d_in[6];
  const float* w3   = (const float*)d_in[7];
  const float* b3   = (const float*)d_in[8];
  float* out = (float*)d_out;

  int N = in_sizes[2];
  int E = in_sizes[1] / 2;
  const int* esrc = ei;
  const int* edst = ei + E;

  int* W = (int*)d_ws;
  int*   deg_i  = W;
  int*   offs   = W + N;
  int*   cursor = W + 2 * N;
  float* dinv   = (float*)(W + 3 * N);
  int*   bsum   = W + 4 * N;
  int*   bofs   = bsum + 64;
  int*   cnt    = bofs + 64;
  float* pooled = (float*)(cnt + 64);
  int*   csr    = (int*)(pooled + N_GRAPHS * HIDDEN);
  float* yb     = (float*)(csr + E);
  float* hb     = yb + (size_t)N * IN_CH;

  hipMemsetAsync(deg_i, 0, (size_t)N * sizeof(int), stream);
  hipMemsetAsync(pooled, 0, (size_t)(N_GRAPHS * HIDDEN) * sizeof(float), stream);

  const int tb = 256;
  k_deg<<<(E + tb - 1) / tb, tb, 0, stream>>>(edst, deg_i, E);
  k_cnt_bs<<<1, 64, 0, stream>>>(batch, cnt, N);
  k_dinv<<<(N + tb - 1) / tb, tb, 0, stream>>>(deg_i, dinv, N);
  int nb = (N + 1023) / 1024;
  k_scan1<<<nb, 1024, 0, stream>>>(deg_i, offs, bsum, N);
  k_scan2<<<1, 64, 0, stream>>>(bsum, bofs, nb);
  k_scan3<<<(N + tb - 1) / tb, tb, 0, stream>>>(offs, cursor, bofs, N);
  k_scatter<<<(E + tb - 1) / tb, tb, 0, stream>>>(esrc, edst, cursor, csr, E);
  k_agg<<<(N * 64 + tb - 1) / tb, tb, 0, stream>>>(x, csr, offs, deg_i, dinv, yb, N);
  k_gemm1<<<(N + GN - 1) / GN, 256, 0, stream>>>(yb, w1, b1, hb, N);
  k_pool<<<256, tb, 0, stream>>>(hb, batch, pooled, N);
  k_head<<<N_GRAPHS, 256, 0, stream>>>(pooled, cnt, w2, b2, w3, b3, out);
}

// Round 3
// 285.826 us; speedup vs baseline: 1.8313x; 1.0329x over previous
//
#include <hip/hip_runtime.h>

#define IN_CH   128
#define HIDDEN  256
#define N_GRAPHS 64
#define GN 64  // nodes per gemm block

__global__ void k_deg(const int* __restrict__ dst, int* __restrict__ deg, int e) {
  int i = blockIdx.x * blockDim.x + threadIdx.x;
  if (i < e) atomicAdd(&deg[dst[i]], 1);
}

__global__ __launch_bounds__(1024) void k_scan1(const int* __restrict__ deg,
    int* __restrict__ offs, int* __restrict__ bsum, int n) {
  __shared__ int sm[1024];
  int t = threadIdx.x;
  int i = blockIdx.x * 1024 + t;
  int v = (i < n) ? deg[i] : 0;
  sm[t] = v;
  __syncthreads();
  for (int d = 1; d < 1024; d <<= 1) {
    int add = (t >= d) ? sm[t - d] : 0;
    __syncthreads();
    sm[t] += add;
    __syncthreads();
  }
  if (i < n) offs[i] = sm[t] - v;  // exclusive
  if (t == 1023) bsum[blockIdx.x] = sm[1023];
}

__global__ void k_scan2(const int* __restrict__ bsum, int* __restrict__ bofs, int nb) {
  if (threadIdx.x == 0 && blockIdx.x == 0) {
    int run = 0;
    for (int b = 0; b < nb; ++b) { bofs[b] = run; run += bsum[b]; }
  }
}

// offs += block offset; cursor = offs; dinv = 1/sqrt(deg+1)  (k_dinv fused)
__global__ void k_scan3(int* __restrict__ offs, int* __restrict__ cursor,
                        const int* __restrict__ bofs, const int* __restrict__ deg,
                        float* __restrict__ dinv, int n) {
  int i = blockIdx.x * blockDim.x + threadIdx.x;
  if (i < n) {
    int o = offs[i] + bofs[i >> 10];
    offs[i] = o;
    cursor[i] = o;
    dinv[i] = 1.0f / sqrtf((float)(deg[i] + 1));
  }
}

__global__ void k_scatter(const int* __restrict__ src, const int* __restrict__ dst,
                          int* __restrict__ cursor, int* __restrict__ csr, int e) {
  int i = blockIdx.x * blockDim.x + threadIdx.x;
  if (i < e) {
    int d = dst[i];
    int pos = atomicAdd(&cursor[d], 1);
    csr[pos] = src[i];
  }
}

// 4 nodes/block. Per wave: lane = es*16+cg; es = edge slot (4), cg = channel
// group (16 x 8 floats). 8 gather rows in flight per wave (2x unroll).
__global__ __launch_bounds__(256) void k_agg(const float* __restrict__ x,
    const int* __restrict__ csr, const int* __restrict__ offs,
    const int* __restrict__ degc, const float* __restrict__ dinv,
    float* __restrict__ y, int n) {
  int node = blockIdx.x * 4 + (threadIdx.x >> 6);
  if (node >= n) return;
  int lane = threadIdx.x & 63;
  int es = lane >> 4;
  int cg = lane & 15;
  int o = offs[node], c = degc[node];
  float4 A0 = {0.f,0.f,0.f,0.f}, A1 = {0.f,0.f,0.f,0.f};
  for (int it = 0; it < c; it += 8) {
    int i0 = it + es, i1 = it + 4 + es;
    int s0 = (i0 < c) ? csr[o + i0] : node;
    int s1 = (i1 < c) ? csr[o + i1] : node;
    float w0 = (i0 < c) ? dinv[s0] : 0.f;
    float w1 = (i1 < c) ? dinv[s1] : 0.f;
    const float4* r0 = reinterpret_cast<const float4*>(&x[(size_t)s0 * IN_CH + cg * 8]);
    const float4* r1 = reinterpret_cast<const float4*>(&x[(size_t)s1 * IN_CH + cg * 8]);
    float4 a0 = r0[0], b0 = r0[1];
    float4 a1 = r1[0], b1 = r1[1];
    A0.x += w0 * a0.x; A0.y += w0 * a0.y; A0.z += w0 * a0.z; A0.w += w0 * a0.w;
    A1.x += w0 * b0.x; A1.y += w0 * b0.y; A1.z += w0 * b0.z; A1.w += w0 * b0.w;
    A0.x += w1 * a1.x; A0.y += w1 * a1.y; A0.z += w1 * a1.z; A0.w += w1 * a1.w;
    A1.x += w1 * b1.x; A1.y += w1 * b1.y; A1.z += w1 * b1.z; A1.w += w1 * b1.w;
  }
  // butterfly-reduce across the 4 edge slots (xor 16, 32)
  float v[8] = {A0.x, A0.y, A0.z, A0.w, A1.x, A1.y, A1.z, A1.w};
#pragma unroll
  for (int k = 0; k < 8; ++k) {
    v[k] += __shfl_xor(v[k], 16, 64);
    v[k] += __shfl_xor(v[k], 32, 64);
  }
  if (es == 0) {
    float dn = dinv[node];
    const float4* xr = reinterpret_cast<const float4*>(&x[(size_t)node * IN_CH + cg * 8]);
    float4 xa = xr[0], xb = xr[1];
    float4 o0, o1;
    o0.x = (v[0] + xa.x * dn) * dn;
    o0.y = (v[1] + xa.y * dn) * dn;
    o0.z = (v[2] + xa.z * dn) * dn;
    o0.w = (v[3] + xa.w * dn) * dn;
    o1.x = (v[4] + xb.x * dn) * dn;
    o1.y = (v[5] + xb.y * dn) * dn;
    o1.z = (v[6] + xb.z * dn) * dn;
    o1.w = (v[7] + xb.w * dn) * dn;
    float4* yr = reinterpret_cast<float4*>(&y[(size_t)node * IN_CH + cg * 8]);
    yr[0] = o0;
    yr[1] = o1;
  }
}

// h[n] = relu(y[n] @ w1 + b1), 64 nodes/block, 256 threads.
__global__ __launch_bounds__(256) void k_gemm1(const float* __restrict__ y,
    const float* __restrict__ w1, const float* __restrict__ b1,
    float* __restrict__ h, int n) {
  __shared__ float ylds[GN * 128];   // 32 KB
  __shared__ float wlds[16 * 256];   // 16 KB
  int t = threadIdx.x;
  int node0 = blockIdx.x * GN;
  {
    const float4* ys = reinterpret_cast<const float4*>(y);
    float4* yd = reinterpret_cast<float4*>(ylds);
    int base4 = node0 * 32, tot4 = n * 32;
#pragma unroll
    for (int i = 0; i < (GN * 32) / 256; ++i) {
      int idx = t + i * 256;
      int g = base4 + idx;
      float4 v = {0.f, 0.f, 0.f, 0.f};
      if (g < tot4) v = ys[g];
      yd[idx] = v;
    }
  }
  int cg = t & 31, ng = t >> 5;
  float acc[8][8];
#pragma unroll
  for (int m = 0; m < 8; ++m)
#pragma unroll
    for (int c = 0; c < 8; ++c) acc[m][c] = 0.f;

  for (int k0 = 0; k0 < 128; k0 += 16) {
    __syncthreads();
    {
      const float4* ws4 = reinterpret_cast<const float4*>(w1 + k0 * 256);
      float4* wd = reinterpret_cast<float4*>(wlds);
#pragma unroll
      for (int i = 0; i < 4; ++i) wd[t + i * 256] = ws4[t + i * 256];
    }
    __syncthreads();
#pragma unroll
    for (int kk = 0; kk < 16; kk += 4) {
      float4 wv0[4], wv1[4];
#pragma unroll
      for (int u = 0; u < 4; ++u) {
        const float* wr = &wlds[(kk + u) * 256 + cg * 4];
        wv0[u] = *reinterpret_cast<const float4*>(wr);
        wv1[u] = *reinterpret_cast<const float4*>(wr + 128);
      }
#pragma unroll
      for (int m = 0; m < 8; ++m) {
        float4 yv = *reinterpret_cast<const float4*>(&ylds[(ng * 8 + m) * 128 + k0 + kk]);
        float ya[4] = {yv.x, yv.y, yv.z, yv.w};
#pragma unroll
        for (int u = 0; u < 4; ++u) {
          acc[m][0] += ya[u] * wv0[u].x;
          acc[m][1] += ya[u] * wv0[u].y;
          acc[m][2] += ya[u] * wv0[u].z;
          acc[m][3] += ya[u] * wv0[u].w;
          acc[m][4] += ya[u] * wv1[u].x;
          acc[m][5] += ya[u] * wv1[u].y;
          acc[m][6] += ya[u] * wv1[u].z;
          acc[m][7] += ya[u] * wv1[u].w;
        }
      }
    }
  }
  float b0[4], b4[4];
#pragma unroll
  for (int u = 0; u < 4; ++u) { b0[u] = b1[cg * 4 + u]; b4[u] = b1[128 + cg * 4 + u]; }
#pragma unroll
  for (int m = 0; m < 8; ++m) {
    int node = node0 + ng * 8 + m;
    if (node < n) {
      float4 o0, o1;
      o0.x = fmaxf(acc[m][0] + b0[0], 0.f);
      o0.y = fmaxf(acc[m][1] + b0[1], 0.f);
      o0.z = fmaxf(acc[m][2] + b0[2], 0.f);
      o0.w = fmaxf(acc[m][3] + b0[3], 0.f);
      o1.x = fmaxf(acc[m][4] + b4[0], 0.f);
      o1.y = fmaxf(acc[m][5] + b4[1], 0.f);
      o1.z = fmaxf(acc[m][6] + b4[2], 0.f);
      o1.w = fmaxf(acc[m][7] + b4[3], 0.f);
      *reinterpret_cast<float4*>(&h[(size_t)node * 256 + cg * 4]) = o0;
      *reinterpret_cast<float4*>(&h[(size_t)node * 256 + 128 + cg * 4]) = o1;
    }
  }
}

// batch is sorted: run-length accumulate, flush per graph-change.
__global__ __launch_bounds__(256) void k_pool(const float* __restrict__ h,
    const int* __restrict__ batch, float* __restrict__ pooled, int n) {
  int per = (n + gridDim.x - 1) / gridDim.x;
  int s = blockIdx.x * per;
  int e_ = min(n, s + per);
  if (s >= e_) return;
  int ch = threadIdx.x;
  float acc = 0.f;
  int g = batch[s];
  for (int i = s; i < e_; ++i) {
    int gi = batch[i];
    if (gi != g) {
      atomicAdd(&pooled[g * HIDDEN + ch], acc);
      acc = 0.f;
      g = gi;
    }
    acc += h[(size_t)i * HIDDEN + ch];
  }
  atomicAdd(&pooled[g * HIDDEN + ch], acc);
}

// One block per graph: cnt via binary search (batch sorted), mean,
// z = relu(p@w2+b2), out = z@w3+b3
__global__ __launch_bounds__(256) void k_head(const float* __restrict__ pooled,
    const int* __restrict__ batch, int n, const float* __restrict__ w2,
    const float* __restrict__ b2, const float* __restrict__ w3,
    const float* __restrict__ b3, float* __restrict__ out) {
  __shared__ float p[256];
  __shared__ float red[4];
  __shared__ int scnt;
  int g = blockIdx.x, t = threadIdx.x;
  if (t == 0) {
    int lo = 0, hi = n;
    while (lo < hi) { int mid = (lo + hi) >> 1; if (batch[mid] < g) lo = mid + 1; else hi = mid; }
    int a = lo;
    lo = 0; hi = n;
    int g1 = g + 1;
    while (lo < hi) { int mid = (lo + hi) >> 1; if (batch[mid] < g1) lo = mid + 1; else hi = mid; }
    scnt = lo - a;
  }
  __syncthreads();
  float c = (float)max(scnt, 1);
  p[t] = pooled[g * HIDDEN + t] / c;
  __syncthreads();
  float a = 0.f;
  for (int k = 0; k < 256; ++k) a += p[k] * w2[k * 256 + t];
  a += b2[t];
  a = fmaxf(a, 0.f);
  float part = a * w3[t];
  for (int off = 32; off > 0; off >>= 1) part += __shfl_down(part, off, 64);
  if ((t & 63) == 0) red[t >> 6] = part;
  __syncthreads();
  if (t == 0) out[g] = red[0] + red[1] + red[2] + red[3] + b3[0];
}

extern "C" void kernel_launch(void* const* d_in, const int* in_sizes, int n_in,
                              void* d_out, int out_size, void* d_ws, size_t ws_size,
                              hipStream_t stream) {
  const float* x    = (const float*)d_in[0];
  const int*   ei   = (const int*)d_in[1];
  const int*   batch= (const int*)d_in[2];
  const float* w1   = (const float*)d_in[3];
  const float* b1   = (const float*)d_in[4];
  const float* w2   = (const float*)d_in[5];
  const float* b2   = (const float*)d_in[6];
  const float* w3   = (const float*)d_in[7];
  const float* b3   = (const float*)d_in[8];
  float* out = (float*)d_out;

  int N = in_sizes[2];
  int E = in_sizes[1] / 2;
  const int* esrc = ei;
  const int* edst = ei + E;

  int* W = (int*)d_ws;
  int*   deg_i  = W;
  int*   offs   = W + N;
  int*   cursor = W + 2 * N;
  float* dinv   = (float*)(W + 3 * N);
  int*   bsum   = W + 4 * N;
  int*   bofs   = bsum + 64;
  float* pooled = (float*)(bofs + 64);
  int*   csr    = (int*)(pooled + N_GRAPHS * HIDDEN);
  float* yb     = (float*)(csr + E);
  float* hb     = yb + (size_t)N * IN_CH;

  hipMemsetAsync(deg_i, 0, (size_t)N * sizeof(int), stream);
  hipMemsetAsync(pooled, 0, (size_t)(N_GRAPHS * HIDDEN) * sizeof(float), stream);

  const int tb = 256;
  k_deg<<<(E + tb - 1) / tb, tb, 0, stream>>>(edst, deg_i, E);
  int nb = (N + 1023) / 1024;
  k_scan1<<<nb, 1024, 0, stream>>>(deg_i, offs, bsum, N);
  k_scan2<<<1, 64, 0, stream>>>(bsum, bofs, nb);
  k_scan3<<<(N + tb - 1) / tb, tb, 0, stream>>>(offs, cursor, bofs, deg_i, dinv, N);
  k_scatter<<<(E + tb - 1) / tb, tb, 0, stream>>>(esrc, edst, cursor, csr, E);
  k_agg<<<(N + 3) / 4, 256, 0, stream>>>(x, csr, offs, deg_i, dinv, yb, N);
  k_gemm1<<<(N + GN - 1) / GN, 256, 0, stream>>>(yb, w1, b1, hb, N);
  k_pool<<<256, tb, 0, stream>>>(hb, batch, pooled, N);
  k_head<<<N_GRAPHS, 256, 0, stream>>>(pooled, batch, N, w2, b2, w3, b3, out);
}

// Round 4
// 266.355 us; speedup vs baseline: 1.9652x; 1.0731x over previous
//
#include <hip/hip_runtime.h>

#define IN_CH   128
#define HIDDEN  256
#define N_GRAPHS 64
#define GN 64  // nodes per fused block

__global__ void k_deg(const int* __restrict__ dst, int* __restrict__ deg, int e) {
  int i = blockIdx.x * blockDim.x + threadIdx.x;
  if (i < e) atomicAdd(&deg[dst[i]], 1);
}

__global__ __launch_bounds__(1024) void k_scan1(const int* __restrict__ deg,
    int* __restrict__ offs, int* __restrict__ bsum, int n) {
  __shared__ int sm[1024];
  int t = threadIdx.x;
  int i = blockIdx.x * 1024 + t;
  int v = (i < n) ? deg[i] : 0;
  sm[t] = v;
  __syncthreads();
  for (int d = 1; d < 1024; d <<= 1) {
    int add = (t >= d) ? sm[t - d] : 0;
    __syncthreads();
    sm[t] += add;
    __syncthreads();
  }
  if (i < n) offs[i] = sm[t] - v;  // exclusive
  if (t == 1023) bsum[blockIdx.x] = sm[1023];
}

__global__ void k_scan2(const int* __restrict__ bsum, int* __restrict__ bofs, int nb) {
  if (threadIdx.x == 0 && blockIdx.x == 0) {
    int run = 0;
    for (int b = 0; b < nb; ++b) { bofs[b] = run; run += bsum[b]; }
  }
}

// offs += block offset; cursor = offs; dinv = 1/sqrt(deg+1)
__global__ void k_scan3(int* __restrict__ offs, int* __restrict__ cursor,
                        const int* __restrict__ bofs, const int* __restrict__ deg,
                        float* __restrict__ dinv, int n) {
  int i = blockIdx.x * blockDim.x + threadIdx.x;
  if (i < n) {
    int o = offs[i] + bofs[i >> 10];
    offs[i] = o;
    cursor[i] = o;
    dinv[i] = 1.0f / sqrtf((float)(deg[i] + 1));
  }
}

__global__ void k_scatter(const int* __restrict__ src, const int* __restrict__ dst,
                          int* __restrict__ cursor, int* __restrict__ csr, int e) {
  int i = blockIdx.x * blockDim.x + threadIdx.x;
  if (i < e) {
    int d = dst[i];
    int pos = atomicAdd(&cursor[d], 1);
    csr[pos] = src[i];
  }
}

// Fused: aggregate 64 nodes into LDS -> GEMM(128->256)+bias+relu -> per-graph pool
__global__ __launch_bounds__(256) void k_fused(
    const float* __restrict__ x, const int* __restrict__ csr,
    const int* __restrict__ offs, const int* __restrict__ degc,
    const float* __restrict__ dinv, const float* __restrict__ w1,
    const float* __restrict__ b1, const int* __restrict__ batch,
    float* __restrict__ pooled, int n) {
  __shared__ float ylds[GN * 128];    // 32 KB aggregated features
  __shared__ float wlds[16 * 256];    // 16 KB w1 chunk
  __shared__ float part[4][HIDDEN];   // 4 KB per-graph partial sums
  __shared__ int bl[GN];
  int t = threadIdx.x;
  int node0 = blockIdx.x * GN;

  if (t < GN) {
    int nd = node0 + t;
    bl[t] = (nd < n) ? batch[nd] : -1;
  }
  {
    float* pp = &part[0][0];
    for (int i = t; i < 4 * HIDDEN; i += 256) pp[i] = 0.f;
  }

  // ---- phase 1: aggregation. wave wv owns rows wv*16..wv*16+15.
  // lane = es*16+cg: es = edge slot (4), cg = channel group (16 x 8 floats).
  {
    int wv = t >> 6, lane = t & 63;
    int es = lane >> 4, cg = lane & 15;
    for (int r = 0; r < 16; ++r) {
      int row = wv * 16 + r;
      int node = node0 + row;
      if (node >= n) break;  // wave-uniform
      int o = offs[node], c = degc[node];
      float4 A0 = {0.f,0.f,0.f,0.f}, A1 = {0.f,0.f,0.f,0.f};
      for (int it = 0; it < c; it += 16) {
        float w[4];
        const float4* rp[4];
#pragma unroll
        for (int u = 0; u < 4; ++u) {
          int ii = it + u * 4 + es;
          bool val = ii < c;
          int s = val ? csr[o + ii] : node;
          w[u] = val ? dinv[s] : 0.f;
          rp[u] = reinterpret_cast<const float4*>(&x[(size_t)s * IN_CH + cg * 8]);
        }
#pragma unroll
        for (int u = 0; u < 4; ++u) {
          float4 a = rp[u][0], b = rp[u][1];
          A0.x += w[u] * a.x; A0.y += w[u] * a.y; A0.z += w[u] * a.z; A0.w += w[u] * a.w;
          A1.x += w[u] * b.x; A1.y += w[u] * b.y; A1.z += w[u] * b.z; A1.w += w[u] * b.w;
        }
      }
      float v[8] = {A0.x, A0.y, A0.z, A0.w, A1.x, A1.y, A1.z, A1.w};
#pragma unroll
      for (int k = 0; k < 8; ++k) {
        v[k] += __shfl_xor(v[k], 16, 64);
        v[k] += __shfl_xor(v[k], 32, 64);
      }
      if (es == 0) {
        float dn = dinv[node];
        const float4* xr = reinterpret_cast<const float4*>(&x[(size_t)node * IN_CH + cg * 8]);
        float4 xa = xr[0], xb = xr[1];
        float4 o0, o1;
        o0.x = (v[0] + xa.x * dn) * dn;
        o0.y = (v[1] + xa.y * dn) * dn;
        o0.z = (v[2] + xa.z * dn) * dn;
        o0.w = (v[3] + xa.w * dn) * dn;
        o1.x = (v[4] + xb.x * dn) * dn;
        o1.y = (v[5] + xb.y * dn) * dn;
        o1.z = (v[6] + xb.z * dn) * dn;
        o1.w = (v[7] + xb.w * dn) * dn;
        float4* yr = reinterpret_cast<float4*>(&ylds[row * 128 + cg * 8]);
        yr[0] = o0;
        yr[1] = o1;
      }
    }
  }

  // ---- phase 2: GEMM. thread (cg2 = t&31, ng = t>>5): 8 nodes x 8 channels.
  int cg2 = t & 31, ng = t >> 5;
  float acc[8][8];
#pragma unroll
  for (int m = 0; m < 8; ++m)
#pragma unroll
    for (int c = 0; c < 8; ++c) acc[m][c] = 0.f;

  for (int k0 = 0; k0 < 128; k0 += 16) {
    __syncthreads();  // first iter: also the agg->gemm barrier
    {
      const float4* ws4 = reinterpret_cast<const float4*>(w1 + k0 * 256);
      float4* wd = reinterpret_cast<float4*>(wlds);
#pragma unroll
      for (int i = 0; i < 4; ++i) wd[t + i * 256] = ws4[t + i * 256];
    }
    __syncthreads();
#pragma unroll
    for (int kk = 0; kk < 16; kk += 4) {
      float4 wv0[4], wv1[4];
#pragma unroll
      for (int u = 0; u < 4; ++u) {
        const float* wr = &wlds[(kk + u) * 256 + cg2 * 4];
        wv0[u] = *reinterpret_cast<const float4*>(wr);
        wv1[u] = *reinterpret_cast<const float4*>(wr + 128);
      }
#pragma unroll
      for (int m = 0; m < 8; ++m) {
        float4 yv = *reinterpret_cast<const float4*>(&ylds[(ng * 8 + m) * 128 + k0 + kk]);
        float ya[4] = {yv.x, yv.y, yv.z, yv.w};
#pragma unroll
        for (int u = 0; u < 4; ++u) {
          acc[m][0] += ya[u] * wv0[u].x;
          acc[m][1] += ya[u] * wv0[u].y;
          acc[m][2] += ya[u] * wv0[u].z;
          acc[m][3] += ya[u] * wv0[u].w;
          acc[m][4] += ya[u] * wv1[u].x;
          acc[m][5] += ya[u] * wv1[u].y;
          acc[m][6] += ya[u] * wv1[u].z;
          acc[m][7] += ya[u] * wv1[u].w;
        }
      }
    }
  }

  // ---- phase 3: relu + per-graph pooled sums (batch sorted => runs)
  float b0[4], b4[4];
#pragma unroll
  for (int u = 0; u < 4; ++u) { b0[u] = b1[cg2 * 4 + u]; b4[u] = b1[128 + cg2 * 4 + u]; }
  int g0 = bl[0];
  float s[8];
#pragma unroll
  for (int u = 0; u < 8; ++u) s[u] = 0.f;
  int gcur = -1;

  auto flush = [&](int g) {
    if (g < 0) return;
    int gi = g - g0;
    if (gi < 4) {
#pragma unroll
      for (int u = 0; u < 4; ++u) {
        atomicAdd(&part[gi][cg2 * 4 + u], s[u]);
        atomicAdd(&part[gi][128 + cg2 * 4 + u], s[4 + u]);
      }
    } else {
#pragma unroll
      for (int u = 0; u < 4; ++u) {
        atomicAdd(&pooled[g * HIDDEN + cg2 * 4 + u], s[u]);
        atomicAdd(&pooled[g * HIDDEN + 128 + cg2 * 4 + u], s[4 + u]);
      }
    }
  };

#pragma unroll
  for (int m = 0; m < 8; ++m) {
    int row = ng * 8 + m;
    int node = node0 + row;
    int g = (node < n) ? bl[row] : -1;
    if (g != gcur) {
      flush(gcur);
#pragma unroll
      for (int u = 0; u < 8; ++u) s[u] = 0.f;
      gcur = g;
    }
    if (g >= 0) {
      s[0] += fmaxf(acc[m][0] + b0[0], 0.f);
      s[1] += fmaxf(acc[m][1] + b0[1], 0.f);
      s[2] += fmaxf(acc[m][2] + b0[2], 0.f);
      s[3] += fmaxf(acc[m][3] + b0[3], 0.f);
      s[4] += fmaxf(acc[m][4] + b4[0], 0.f);
      s[5] += fmaxf(acc[m][5] + b4[1], 0.f);
      s[6] += fmaxf(acc[m][6] + b4[2], 0.f);
      s[7] += fmaxf(acc[m][7] + b4[3], 0.f);
    }
  }
  flush(gcur);

  __syncthreads();
  int lastIdx = min(GN, n - node0) - 1;
  int gmax = bl[lastIdx];
  int span = gmax - g0;
  if (span > 3) span = 3;
  for (int gi = 0; gi <= span; ++gi) {
    atomicAdd(&pooled[(g0 + gi) * HIDDEN + t], part[gi][t]);
  }
}

// One block per graph: cnt via binary search (batch sorted), mean,
// z = relu(p@w2+b2), out = z@w3+b3
__global__ __launch_bounds__(256) void k_head(const float* __restrict__ pooled,
    const int* __restrict__ batch, int n, const float* __restrict__ w2,
    const float* __restrict__ b2, const float* __restrict__ w3,
    const float* __restrict__ b3, float* __restrict__ out) {
  __shared__ float p[256];
  __shared__ float red[4];
  __shared__ int scnt;
  int g = blockIdx.x, t = threadIdx.x;
  if (t == 0) {
    int lo = 0, hi = n;
    while (lo < hi) { int mid = (lo + hi) >> 1; if (batch[mid] < g) lo = mid + 1; else hi = mid; }
    int a = lo;
    lo = 0; hi = n;
    int g1 = g + 1;
    while (lo < hi) { int mid = (lo + hi) >> 1; if (batch[mid] < g1) lo = mid + 1; else hi = mid; }
    scnt = lo - a;
  }
  __syncthreads();
  float c = (float)max(scnt, 1);
  p[t] = pooled[g * HIDDEN + t] / c;
  __syncthreads();
  float a = 0.f;
  for (int k = 0; k < 256; ++k) a += p[k] * w2[k * 256 + t];
  a += b2[t];
  a = fmaxf(a, 0.f);
  float part = a * w3[t];
  for (int off = 32; off > 0; off >>= 1) part += __shfl_down(part, off, 64);
  if ((t & 63) == 0) red[t >> 6] = part;
  __syncthreads();
  if (t == 0) out[g] = red[0] + red[1] + red[2] + red[3] + b3[0];
}

extern "C" void kernel_launch(void* const* d_in, const int* in_sizes, int n_in,
                              void* d_out, int out_size, void* d_ws, size_t ws_size,
                              hipStream_t stream) {
  const float* x    = (const float*)d_in[0];
  const int*   ei   = (const int*)d_in[1];
  const int*   batch= (const int*)d_in[2];
  const float* w1   = (const float*)d_in[3];
  const float* b1   = (const float*)d_in[4];
  const float* w2   = (const float*)d_in[5];
  const float* b2   = (const float*)d_in[6];
  const float* w3   = (const float*)d_in[7];
  const float* b3   = (const float*)d_in[8];
  float* out = (float*)d_out;

  int N = in_sizes[2];
  int E = in_sizes[1] / 2;
  const int* esrc = ei;
  const int* edst = ei + E;

  int* W = (int*)d_ws;
  int*   deg_i  = W;
  int*   offs   = W + N;
  int*   cursor = W + 2 * N;
  float* dinv   = (float*)(W + 3 * N);
  int*   bsum   = W + 4 * N;
  int*   bofs   = bsum + 64;
  float* pooled = (float*)(bofs + 64);
  int*   csr    = (int*)(pooled + N_GRAPHS * HIDDEN);

  hipMemsetAsync(deg_i, 0, (size_t)N * sizeof(int), stream);
  hipMemsetAsync(pooled, 0, (size_t)(N_GRAPHS * HIDDEN) * sizeof(float), stream);

  const int tb = 256;
  k_deg<<<(E + tb - 1) / tb, tb, 0, stream>>>(edst, deg_i, E);
  int nb = (N + 1023) / 1024;
  k_scan1<<<nb, 1024, 0, stream>>>(deg_i, offs, bsum, N);
  k_scan2<<<1, 64, 0, stream>>>(bsum, bofs, nb);
  k_scan3<<<(N + tb - 1) / tb, tb, 0, stream>>>(offs, cursor, bofs, deg_i, dinv, N);
  k_scatter<<<(E + tb - 1) / tb, tb, 0, stream>>>(esrc, edst, cursor, csr, E);
  k_fused<<<(N + GN - 1) / GN, 256, 0, stream>>>(x, csr, offs, deg_i, dinv,
                                                 w1, b1, batch, pooled, N);
  k_head<<<N_GRAPHS, 256, 0, stream>>>(pooled, batch, N, w2, b2, w3, b3, out);
}

// Round 5
// 259.184 us; speedup vs baseline: 2.0195x; 1.0277x over previous
//
#include <hip/hip_runtime.h>

#define IN_CH   128
#define HIDDEN  256
#define N_GRAPHS 64
#define GN 64  // nodes per gemm block

__global__ void k_deg(const int* __restrict__ dst, int* __restrict__ deg, int e) {
  int i = blockIdx.x * blockDim.x + threadIdx.x;
  if (i < e) atomicAdd(&deg[dst[i]], 1);
}

__global__ __launch_bounds__(1024) void k_scan1(const int* __restrict__ deg,
    int* __restrict__ offs, int* __restrict__ bsum, int n) {
  __shared__ int sm[1024];
  int t = threadIdx.x;
  int i = blockIdx.x * 1024 + t;
  int v = (i < n) ? deg[i] : 0;
  sm[t] = v;
  __syncthreads();
  for (int d = 1; d < 1024; d <<= 1) {
    int add = (t >= d) ? sm[t - d] : 0;
    __syncthreads();
    sm[t] += add;
    __syncthreads();
  }
  if (i < n) offs[i] = sm[t] - v;  // exclusive
  if (t == 1023) bsum[blockIdx.x] = sm[1023];
}

__global__ void k_scan2(const int* __restrict__ bsum, int* __restrict__ bofs, int nb) {
  if (threadIdx.x == 0 && blockIdx.x == 0) {
    int run = 0;
    for (int b = 0; b < nb; ++b) { bofs[b] = run; run += bsum[b]; }
  }
}

// offs += block offset; cursor = offs; dinv = 1/sqrt(deg+1)
__global__ void k_scan3(int* __restrict__ offs, int* __restrict__ cursor,
                        const int* __restrict__ bofs, const int* __restrict__ deg,
                        float* __restrict__ dinv, int n) {
  int i = blockIdx.x * blockDim.x + threadIdx.x;
  if (i < n) {
    int o = offs[i] + bofs[i >> 10];
    offs[i] = o;
    cursor[i] = o;
    dinv[i] = 1.0f / sqrtf((float)(deg[i] + 1));
  }
}

__global__ void k_scatter(const int* __restrict__ src, const int* __restrict__ dst,
                          int* __restrict__ cursor, int* __restrict__ csr, int e) {
  int i = blockIdx.x * blockDim.x + threadIdx.x;
  if (i < e) {
    int d = dst[i];
    int pos = atomicAdd(&cursor[d], 1);
    csr[pos] = src[i];
  }
}

// 4 nodes/block, high occupancy (0 LDS, ~16 VGPR). lane = es*16+cg;
// es = edge slot (4), cg = channel group (16 x 8 floats). 8 rows in flight.
__global__ __launch_bounds__(256) void k_agg(const float* __restrict__ x,
    const int* __restrict__ csr, const int* __restrict__ offs,
    const int* __restrict__ degc, const float* __restrict__ dinv,
    float* __restrict__ y, int n) {
  int node = blockIdx.x * 4 + (threadIdx.x >> 6);
  if (node >= n) return;
  int lane = threadIdx.x & 63;
  int es = lane >> 4;
  int cg = lane & 15;
  int o = offs[node], c = degc[node];
  float4 A0 = {0.f,0.f,0.f,0.f}, A1 = {0.f,0.f,0.f,0.f};
  for (int it = 0; it < c; it += 8) {
    int i0 = it + es, i1 = it + 4 + es;
    int s0 = (i0 < c) ? csr[o + i0] : node;
    int s1 = (i1 < c) ? csr[o + i1] : node;
    float w0 = (i0 < c) ? dinv[s0] : 0.f;
    float w1 = (i1 < c) ? dinv[s1] : 0.f;
    const float4* r0 = reinterpret_cast<const float4*>(&x[(size_t)s0 * IN_CH + cg * 8]);
    const float4* r1 = reinterpret_cast<const float4*>(&x[(size_t)s1 * IN_CH + cg * 8]);
    float4 a0 = r0[0], b0 = r0[1];
    float4 a1 = r1[0], b1 = r1[1];
    A0.x += w0 * a0.x; A0.y += w0 * a0.y; A0.z += w0 * a0.z; A0.w += w0 * a0.w;
    A1.x += w0 * b0.x; A1.y += w0 * b0.y; A1.z += w0 * b0.z; A1.w += w0 * b0.w;
    A0.x += w1 * a1.x; A0.y += w1 * a1.y; A0.z += w1 * a1.z; A0.w += w1 * a1.w;
    A1.x += w1 * b1.x; A1.y += w1 * b1.y; A1.z += w1 * b1.z; A1.w += w1 * b1.w;
  }
  float v[8] = {A0.x, A0.y, A0.z, A0.w, A1.x, A1.y, A1.z, A1.w};
#pragma unroll
  for (int k = 0; k < 8; ++k) {
    v[k] += __shfl_xor(v[k], 16, 64);
    v[k] += __shfl_xor(v[k], 32, 64);
  }
  if (es == 0) {
    float dn = dinv[node];
    const float4* xr = reinterpret_cast<const float4*>(&x[(size_t)node * IN_CH + cg * 8]);
    float4 xa = xr[0], xb = xr[1];
    float4 o0, o1;
    o0.x = (v[0] + xa.x * dn) * dn;
    o0.y = (v[1] + xa.y * dn) * dn;
    o0.z = (v[2] + xa.z * dn) * dn;
    o0.w = (v[3] + xa.w * dn) * dn;
    o1.x = (v[4] + xb.x * dn) * dn;
    o1.y = (v[5] + xb.y * dn) * dn;
    o1.z = (v[6] + xb.z * dn) * dn;
    o1.w = (v[7] + xb.w * dn) * dn;
    float4* yr = reinterpret_cast<float4*>(&y[(size_t)node * IN_CH + cg * 8]);
    yr[0] = o0;
    yr[1] = o1;
  }
}

// GEMM(128->256)+bias+relu fused with per-graph pooling. 64 nodes/block,
// 256 threads, thread tile 8 nodes x 8 channels. w1 chunk prefetched to
// registers one chunk ahead so global latency hides under the FMAs.
__global__ __launch_bounds__(256, 4) void k_gemmpool(
    const float* __restrict__ y, const float* __restrict__ w1,
    const float* __restrict__ b1, const int* __restrict__ batch,
    float* __restrict__ pooled, int n) {
  __shared__ float ylds[GN * 128];   // 32 KB
  __shared__ float wlds[16 * 256];   // 16 KB
  __shared__ float part[4][HIDDEN];  // 4 KB
  __shared__ int bl[GN];
  int t = threadIdx.x;
  int node0 = blockIdx.x * GN;

  if (t < GN) {
    int nd = node0 + t;
    bl[t] = (nd < n) ? batch[nd] : -1;
  }
  {
    float* pp = &part[0][0];
    for (int i = t; i < 4 * HIDDEN; i += 256) pp[i] = 0.f;
  }
  {
    const float4* ys = reinterpret_cast<const float4*>(y);
    float4* yd = reinterpret_cast<float4*>(ylds);
    int base4 = node0 * 32, tot4 = n * 32;
#pragma unroll
    for (int i = 0; i < (GN * 32) / 256; ++i) {
      int idx = t + i * 256;
      int g = base4 + idx;
      float4 v = {0.f, 0.f, 0.f, 0.f};
      if (g < tot4) v = ys[g];
      yd[idx] = v;
    }
  }

  int cg2 = t & 31, ng = t >> 5;
  float acc[8][8];
#pragma unroll
  for (int m = 0; m < 8; ++m)
#pragma unroll
    for (int c = 0; c < 8; ++c) acc[m][c] = 0.f;

  // prefetch chunk 0 into registers
  float4 wpre[4];
  {
    const float4* ws4 = reinterpret_cast<const float4*>(w1);
#pragma unroll
    for (int i = 0; i < 4; ++i) wpre[i] = ws4[t + i * 256];
  }

  for (int c8 = 0; c8 < 8; ++c8) {
    __syncthreads();  // protect wlds from previous chunk's readers (+ ylds ready on c8=0)
    {
      float4* wd = reinterpret_cast<float4*>(wlds);
#pragma unroll
      for (int i = 0; i < 4; ++i) wd[t + i * 256] = wpre[i];
    }
    __syncthreads();
    if (c8 < 7) {  // issue next chunk's loads; waited on at next iter's ds_write
      const float4* ws4 = reinterpret_cast<const float4*>(w1 + (c8 + 1) * 16 * 256);
#pragma unroll
      for (int i = 0; i < 4; ++i) wpre[i] = ws4[t + i * 256];
    }
    int k0 = c8 * 16;
#pragma unroll
    for (int kk = 0; kk < 16; kk += 4) {
      float4 wv0[4], wv1[4];
#pragma unroll
      for (int u = 0; u < 4; ++u) {
        const float* wr = &wlds[(kk + u) * 256 + cg2 * 4];
        wv0[u] = *reinterpret_cast<const float4*>(wr);
        wv1[u] = *reinterpret_cast<const float4*>(wr + 128);
      }
#pragma unroll
      for (int m = 0; m < 8; ++m) {
        float4 yv = *reinterpret_cast<const float4*>(&ylds[(ng * 8 + m) * 128 + k0 + kk]);
        float ya[4] = {yv.x, yv.y, yv.z, yv.w};
#pragma unroll
        for (int u = 0; u < 4; ++u) {
          acc[m][0] += ya[u] * wv0[u].x;
          acc[m][1] += ya[u] * wv0[u].y;
          acc[m][2] += ya[u] * wv0[u].z;
          acc[m][3] += ya[u] * wv0[u].w;
          acc[m][4] += ya[u] * wv1[u].x;
          acc[m][5] += ya[u] * wv1[u].y;
          acc[m][6] += ya[u] * wv1[u].z;
          acc[m][7] += ya[u] * wv1[u].w;
        }
      }
    }
  }

  // relu + per-graph pooled sums (batch sorted => runs)
  float b0[4], b4[4];
#pragma unroll
  for (int u = 0; u < 4; ++u) { b0[u] = b1[cg2 * 4 + u]; b4[u] = b1[128 + cg2 * 4 + u]; }
  int g0 = bl[0];
  float s[8];
#pragma unroll
  for (int u = 0; u < 8; ++u) s[u] = 0.f;
  int gcur = -1;

  auto flush = [&](int g) {
    if (g < 0) return;
    int gi = g - g0;
    if (gi < 4) {
#pragma unroll
      for (int u = 0; u < 4; ++u) {
        atomicAdd(&part[gi][cg2 * 4 + u], s[u]);
        atomicAdd(&part[gi][128 + cg2 * 4 + u], s[4 + u]);
      }
    } else {
#pragma unroll
      for (int u = 0; u < 4; ++u) {
        atomicAdd(&pooled[g * HIDDEN + cg2 * 4 + u], s[u]);
        atomicAdd(&pooled[g * HIDDEN + 128 + cg2 * 4 + u], s[4 + u]);
      }
    }
  };

#pragma unroll
  for (int m = 0; m < 8; ++m) {
    int row = ng * 8 + m;
    int node = node0 + row;
    int g = (node < n) ? bl[row] : -1;
    if (g != gcur) {
      flush(gcur);
#pragma unroll
      for (int u = 0; u < 8; ++u) s[u] = 0.f;
      gcur = g;
    }
    if (g >= 0) {
      s[0] += fmaxf(acc[m][0] + b0[0], 0.f);
      s[1] += fmaxf(acc[m][1] + b0[1], 0.f);
      s[2] += fmaxf(acc[m][2] + b0[2], 0.f);
      s[3] += fmaxf(acc[m][3] + b0[3], 0.f);
      s[4] += fmaxf(acc[m][4] + b4[0], 0.f);
      s[5] += fmaxf(acc[m][5] + b4[1], 0.f);
      s[6] += fmaxf(acc[m][6] + b4[2], 0.f);
      s[7] += fmaxf(acc[m][7] + b4[3], 0.f);
    }
  }
  flush(gcur);

  __syncthreads();
  int lastIdx = min(GN, n - node0) - 1;
  int gmax = bl[lastIdx];
  int span = gmax - g0;
  if (span > 3) span = 3;
  for (int gi = 0; gi <= span; ++gi) {
    atomicAdd(&pooled[(g0 + gi) * HIDDEN + t], part[gi][t]);
  }
}

// One block per graph: cnt via binary search (batch sorted), mean,
// z = relu(p@w2+b2), out = z@w3+b3
__global__ __launch_bounds__(256) void k_head(const float* __restrict__ pooled,
    const int* __restrict__ batch, int n, const float* __restrict__ w2,
    const float* __restrict__ b2, const float* __restrict__ w3,
    const float* __restrict__ b3, float* __restrict__ out) {
  __shared__ float p[256];
  __shared__ float red[4];
  __shared__ int scnt;
  int g = blockIdx.x, t = threadIdx.x;
  if (t == 0) {
    int lo = 0, hi = n;
    while (lo < hi) { int mid = (lo + hi) >> 1; if (batch[mid] < g) lo = mid + 1; else hi = mid; }
    int a = lo;
    lo = 0; hi = n;
    int g1 = g + 1;
    while (lo < hi) { int mid = (lo + hi) >> 1; if (batch[mid] < g1) lo = mid + 1; else hi = mid; }
    scnt = lo - a;
  }
  __syncthreads();
  float c = (float)max(scnt, 1);
  p[t] = pooled[g * HIDDEN + t] / c;
  __syncthreads();
  float a = 0.f;
  for (int k = 0; k < 256; ++k) a += p[k] * w2[k * 256 + t];
  a += b2[t];
  a = fmaxf(a, 0.f);
  float part = a * w3[t];
  for (int off = 32; off > 0; off >>= 1) part += __shfl_down(part, off, 64);
  if ((t & 63) == 0) red[t >> 6] = part;
  __syncthreads();
  if (t == 0) out[g] = red[0] + red[1] + red[2] + red[3] + b3[0];
}

extern "C" void kernel_launch(void* const* d_in, const int* in_sizes, int n_in,
                              void* d_out, int out_size, void* d_ws, size_t ws_size,
                              hipStream_t stream) {
  const float* x    = (const float*)d_in[0];
  const int*   ei   = (const int*)d_in[1];
  const int*   batch= (const int*)d_in[2];
  const float* w1   = (const float*)d_in[3];
  const float* b1   = (const float*)d_in[4];
  const float* w2   = (const float*)d_in[5];
  const float* b2   = (const float*)d_in[6];
  const float* w3   = (const float*)d_in[7];
  const float* b3   = (const float*)d_in[8];
  float* out = (float*)d_out;

  int N = in_sizes[2];
  int E = in_sizes[1] / 2;
  const int* esrc = ei;
  const int* edst = ei + E;

  int* W = (int*)d_ws;
  int*   deg_i  = W;
  int*   offs   = W + N;
  int*   cursor = W + 2 * N;
  float* dinv   = (float*)(W + 3 * N);
  int*   bsum   = W + 4 * N;
  int*   bofs   = bsum + 64;
  float* pooled = (float*)(bofs + 64);
  int*   csr    = (int*)(pooled + N_GRAPHS * HIDDEN);
  float* yb     = (float*)(csr + E);

  hipMemsetAsync(deg_i, 0, (size_t)N * sizeof(int), stream);
  hipMemsetAsync(pooled, 0, (size_t)(N_GRAPHS * HIDDEN) * sizeof(float), stream);

  const int tb = 256;
  k_deg<<<(E + tb - 1) / tb, tb, 0, stream>>>(edst, deg_i, E);
  int nb = (N + 1023) / 1024;
  k_scan1<<<nb, 1024, 0, stream>>>(deg_i, offs, bsum, N);
  k_scan2<<<1, 64, 0, stream>>>(bsum, bofs, nb);
  k_scan3<<<(N + tb - 1) / tb, tb, 0, stream>>>(offs, cursor, bofs, deg_i, dinv, N);
  k_scatter<<<(E + tb - 1) / tb, tb, 0, stream>>>(esrc, edst, cursor, csr, E);
  k_agg<<<(N + 3) / 4, 256, 0, stream>>>(x, csr, offs, deg_i, dinv, yb, N);
  k_gemmpool<<<(N + GN - 1) / GN, 256, 0, stream>>>(yb, w1, b1, batch, pooled, N);
  k_head<<<N_GRAPHS, 256, 0, stream>>>(pooled, batch, N, w2, b2, w3, b3, out);
}

// Round 6
// 199.063 us; speedup vs baseline: 2.6295x; 1.3020x over previous
//
#include <hip/hip_runtime.h>

#define IN_CH   128
#define HIDDEN  256
#define N_GRAPHS 64
#define GN 64  // nodes per gemm block

// deg count + per-edge rank within its dst bucket (the same atomic does both)
__global__ void k_deg(const int* __restrict__ dst, int* __restrict__ deg,
                      int* __restrict__ rank, int e) {
  int i = blockIdx.x * blockDim.x + threadIdx.x;
  if (i < e) rank[i] = atomicAdd(&deg[dst[i]], 1);
}

__global__ __launch_bounds__(1024) void k_scan1(const int* __restrict__ deg,
    int* __restrict__ offs, int* __restrict__ bsum, int n) {
  __shared__ int sm[1024];
  int t = threadIdx.x;
  int i = blockIdx.x * 1024 + t;
  int v = (i < n) ? deg[i] : 0;
  sm[t] = v;
  __syncthreads();
  for (int d = 1; d < 1024; d <<= 1) {
    int add = (t >= d) ? sm[t - d] : 0;
    __syncthreads();
    sm[t] += add;
    __syncthreads();
  }
  if (i < n) offs[i] = sm[t] - v;  // exclusive
  if (t == 1023) bsum[blockIdx.x] = sm[1023];
}

__global__ void k_scan2(const int* __restrict__ bsum, int* __restrict__ bofs, int nb) {
  if (threadIdx.x == 0 && blockIdx.x == 0) {
    int run = 0;
    for (int b = 0; b < nb; ++b) { bofs[b] = run; run += bsum[b]; }
  }
}

// offs += block offset; dinv = 1/sqrt(deg+1)
__global__ void k_scan3(int* __restrict__ offs, const int* __restrict__ bofs,
                        const int* __restrict__ deg, float* __restrict__ dinv, int n) {
  int i = blockIdx.x * blockDim.x + threadIdx.x;
  if (i < n) {
    offs[i] += bofs[i >> 10];
    dinv[i] = 1.0f / sqrtf((float)(deg[i] + 1));
  }
}

// atomic-free CSR fill using precomputed ranks
__global__ void k_place(const int* __restrict__ src, const int* __restrict__ dst,
                        const int* __restrict__ rank, const int* __restrict__ offs,
                        int* __restrict__ csr, int e) {
  int i = blockIdx.x * blockDim.x + threadIdx.x;
  if (i < e) csr[offs[dst[i]] + rank[i]] = src[i];
}

// 4 nodes/block, high occupancy (0 LDS, low VGPR). lane = es*16+cg;
// es = edge slot (4), cg = channel group (16 x 8 floats). 8 rows in flight,
// zero wasted loads (bounds checked before issuing).
__global__ __launch_bounds__(256) void k_agg(const float* __restrict__ x,
    const int* __restrict__ csr, const int* __restrict__ offs,
    const int* __restrict__ degc, const float* __restrict__ dinv,
    float* __restrict__ y, int n) {
  int node = blockIdx.x * 4 + (threadIdx.x >> 6);
  if (node >= n) return;
  int lane = threadIdx.x & 63;
  int es = lane >> 4;
  int cg = lane & 15;
  int o = offs[node], c = degc[node];
  float4 A0 = {0.f,0.f,0.f,0.f}, A1 = {0.f,0.f,0.f,0.f};
  int ii = es;
  for (; ii + 4 < c; ii += 8) {
    int s0 = csr[o + ii];
    int s1 = csr[o + ii + 4];
    float w0 = dinv[s0];
    float w1 = dinv[s1];
    const float4* r0 = reinterpret_cast<const float4*>(&x[(size_t)s0 * IN_CH + cg * 8]);
    const float4* r1 = reinterpret_cast<const float4*>(&x[(size_t)s1 * IN_CH + cg * 8]);
    float4 a0 = r0[0], b0 = r0[1];
    float4 a1 = r1[0], b1 = r1[1];
    A0.x += w0 * a0.x; A0.y += w0 * a0.y; A0.z += w0 * a0.z; A0.w += w0 * a0.w;
    A1.x += w0 * b0.x; A1.y += w0 * b0.y; A1.z += w0 * b0.z; A1.w += w0 * b0.w;
    A0.x += w1 * a1.x; A0.y += w1 * a1.y; A0.z += w1 * a1.z; A0.w += w1 * a1.w;
    A1.x += w1 * b1.x; A1.y += w1 * b1.y; A1.z += w1 * b1.z; A1.w += w1 * b1.w;
  }
  if (ii < c) {
    int s0 = csr[o + ii];
    float w0 = dinv[s0];
    const float4* r0 = reinterpret_cast<const float4*>(&x[(size_t)s0 * IN_CH + cg * 8]);
    float4 a0 = r0[0], b0 = r0[1];
    A0.x += w0 * a0.x; A0.y += w0 * a0.y; A0.z += w0 * a0.z; A0.w += w0 * a0.w;
    A1.x += w0 * b0.x; A1.y += w0 * b0.y; A1.z += w0 * b0.z; A1.w += w0 * b0.w;
  }
  float v[8] = {A0.x, A0.y, A0.z, A0.w, A1.x, A1.y, A1.z, A1.w};
#pragma unroll
  for (int k = 0; k < 8; ++k) {
    v[k] += __shfl_xor(v[k], 16, 64);
    v[k] += __shfl_xor(v[k], 32, 64);
  }
  if (es == 0) {
    float dn = dinv[node];
    const float4* xr = reinterpret_cast<const float4*>(&x[(size_t)node * IN_CH + cg * 8]);
    float4 xa = xr[0], xb = xr[1];
    float4 o0, o1;
    o0.x = (v[0] + xa.x * dn) * dn;
    o0.y = (v[1] + xa.y * dn) * dn;
    o0.z = (v[2] + xa.z * dn) * dn;
    o0.w = (v[3] + xa.w * dn) * dn;
    o1.x = (v[4] + xb.x * dn) * dn;
    o1.y = (v[5] + xb.y * dn) * dn;
    o1.z = (v[6] + xb.z * dn) * dn;
    o1.w = (v[7] + xb.w * dn) * dn;
    float4* yr = reinterpret_cast<float4*>(&y[(size_t)node * IN_CH + cg * 8]);
    yr[0] = o0;
    yr[1] = o1;
  }
}

// GEMM(128->256)+bias+relu fused with per-graph pooling. 64 nodes/block,
// 256 threads, thread tile 8 nodes x 8 channels. Simple proven staging.
__global__ __launch_bounds__(256) void k_gemmpool(
    const float* __restrict__ y, const float* __restrict__ w1,
    const float* __restrict__ b1, const int* __restrict__ batch,
    float* __restrict__ pooled, int n) {
  __shared__ float ylds[GN * 128];   // 32 KB
  __shared__ float wlds[16 * 256];   // 16 KB
  __shared__ float part[4][HIDDEN];  // 4 KB
  __shared__ int bl[GN];
  int t = threadIdx.x;
  int node0 = blockIdx.x * GN;

  if (t < GN) {
    int nd = node0 + t;
    bl[t] = (nd < n) ? batch[nd] : -1;
  }
  {
    float* pp = &part[0][0];
    for (int i = t; i < 4 * HIDDEN; i += 256) pp[i] = 0.f;
  }
  {
    const float4* ys = reinterpret_cast<const float4*>(y);
    float4* yd = reinterpret_cast<float4*>(ylds);
    int base4 = node0 * 32, tot4 = n * 32;
#pragma unroll
    for (int i = 0; i < (GN * 32) / 256; ++i) {
      int idx = t + i * 256;
      int g = base4 + idx;
      float4 v = {0.f, 0.f, 0.f, 0.f};
      if (g < tot4) v = ys[g];
      yd[idx] = v;
    }
  }

  int cg2 = t & 31, ng = t >> 5;
  float acc[8][8];
#pragma unroll
  for (int m = 0; m < 8; ++m)
#pragma unroll
    for (int c = 0; c < 8; ++c) acc[m][c] = 0.f;

  for (int k0 = 0; k0 < 128; k0 += 16) {
    __syncthreads();
    {
      const float4* ws4 = reinterpret_cast<const float4*>(w1 + k0 * 256);
      float4* wd = reinterpret_cast<float4*>(wlds);
#pragma unroll
      for (int i = 0; i < 4; ++i) wd[t + i * 256] = ws4[t + i * 256];
    }
    __syncthreads();
#pragma unroll
    for (int kk = 0; kk < 16; kk += 4) {
      float4 wv0[4], wv1[4];
#pragma unroll
      for (int u = 0; u < 4; ++u) {
        const float* wr = &wlds[(kk + u) * 256 + cg2 * 4];
        wv0[u] = *reinterpret_cast<const float4*>(wr);
        wv1[u] = *reinterpret_cast<const float4*>(wr + 128);
      }
#pragma unroll
      for (int m = 0; m < 8; ++m) {
        float4 yv = *reinterpret_cast<const float4*>(&ylds[(ng * 8 + m) * 128 + k0 + kk]);
        float ya[4] = {yv.x, yv.y, yv.z, yv.w};
#pragma unroll
        for (int u = 0; u < 4; ++u) {
          acc[m][0] += ya[u] * wv0[u].x;
          acc[m][1] += ya[u] * wv0[u].y;
          acc[m][2] += ya[u] * wv0[u].z;
          acc[m][3] += ya[u] * wv0[u].w;
          acc[m][4] += ya[u] * wv1[u].x;
          acc[m][5] += ya[u] * wv1[u].y;
          acc[m][6] += ya[u] * wv1[u].z;
          acc[m][7] += ya[u] * wv1[u].w;
        }
      }
    }
  }

  // relu + per-graph pooled sums (batch sorted => runs)
  float b0[4], b4[4];
#pragma unroll
  for (int u = 0; u < 4; ++u) { b0[u] = b1[cg2 * 4 + u]; b4[u] = b1[128 + cg2 * 4 + u]; }
  int g0 = bl[0];
  float s[8];
#pragma unroll
  for (int u = 0; u < 8; ++u) s[u] = 0.f;
  int gcur = -1;

  auto flush = [&](int g) {
    if (g < 0) return;
    int gi = g - g0;
    if (gi < 4) {
#pragma unroll
      for (int u = 0; u < 4; ++u) {
        atomicAdd(&part[gi][cg2 * 4 + u], s[u]);
        atomicAdd(&part[gi][128 + cg2 * 4 + u], s[4 + u]);
      }
    } else {
#pragma unroll
      for (int u = 0; u < 4; ++u) {
        atomicAdd(&pooled[g * HIDDEN + cg2 * 4 + u], s[u]);
        atomicAdd(&pooled[g * HIDDEN + 128 + cg2 * 4 + u], s[4 + u]);
      }
    }
  };

#pragma unroll
  for (int m = 0; m < 8; ++m) {
    int row = ng * 8 + m;
    int node = node0 + row;
    int g = (node < n) ? bl[row] : -1;
    if (g != gcur) {
      flush(gcur);
#pragma unroll
      for (int u = 0; u < 8; ++u) s[u] = 0.f;
      gcur = g;
    }
    if (g >= 0) {
      s[0] += fmaxf(acc[m][0] + b0[0], 0.f);
      s[1] += fmaxf(acc[m][1] + b0[1], 0.f);
      s[2] += fmaxf(acc[m][2] + b0[2], 0.f);
      s[3] += fmaxf(acc[m][3] + b0[3], 0.f);
      s[4] += fmaxf(acc[m][4] + b4[0], 0.f);
      s[5] += fmaxf(acc[m][5] + b4[1], 0.f);
      s[6] += fmaxf(acc[m][6] + b4[2], 0.f);
      s[7] += fmaxf(acc[m][7] + b4[3], 0.f);
    }
  }
  flush(gcur);

  __syncthreads();
  int lastIdx = min(GN, n - node0) - 1;
  int gmax = bl[lastIdx];
  int span = gmax - g0;
  if (span > 3) span = 3;
  for (int gi = 0; gi <= span; ++gi) {
    atomicAdd(&pooled[(g0 + gi) * HIDDEN + t], part[gi][t]);
  }
}

// One block per graph: cnt via binary search (batch sorted), mean,
// z = relu(p@w2+b2), out = z@w3+b3
__global__ __launch_bounds__(256) void k_head(const float* __restrict__ pooled,
    const int* __restrict__ batch, int n, const float* __restrict__ w2,
    const float* __restrict__ b2, const float* __restrict__ w3,
    const float* __restrict__ b3, float* __restrict__ out) {
  __shared__ float p[256];
  __shared__ float red[4];
  __shared__ int scnt;
  int g = blockIdx.x, t = threadIdx.x;
  if (t == 0) {
    int lo = 0, hi = n;
    while (lo < hi) { int mid = (lo + hi) >> 1; if (batch[mid] < g) lo = mid + 1; else hi = mid; }
    int a = lo;
    lo = 0; hi = n;
    int g1 = g + 1;
    while (lo < hi) { int mid = (lo + hi) >> 1; if (batch[mid] < g1) lo = mid + 1; else hi = mid; }
    scnt = lo - a;
  }
  __syncthreads();
  float c = (float)max(scnt, 1);
  p[t] = pooled[g * HIDDEN + t] / c;
  __syncthreads();
  float a = 0.f;
  for (int k = 0; k < 256; ++k) a += p[k] * w2[k * 256 + t];
  a += b2[t];
  a = fmaxf(a, 0.f);
  float part = a * w3[t];
  for (int off = 32; off > 0; off >>= 1) part += __shfl_down(part, off, 64);
  if ((t & 63) == 0) red[t >> 6] = part;
  __syncthreads();
  if (t == 0) out[g] = red[0] + red[1] + red[2] + red[3] + b3[0];
}

extern "C" void kernel_launch(void* const* d_in, const int* in_sizes, int n_in,
                              void* d_out, int out_size, void* d_ws, size_t ws_size,
                              hipStream_t stream) {
  const float* x    = (const float*)d_in[0];
  const int*   ei   = (const int*)d_in[1];
  const int*   batch= (const int*)d_in[2];
  const float* w1   = (const float*)d_in[3];
  const float* b1   = (const float*)d_in[4];
  const float* w2   = (const float*)d_in[5];
  const float* b2   = (const float*)d_in[6];
  const float* w3   = (const float*)d_in[7];
  const float* b3   = (const float*)d_in[8];
  float* out = (float*)d_out;

  int N = in_sizes[2];
  int E = in_sizes[1] / 2;
  const int* esrc = ei;
  const int* edst = ei + E;

  // layout: [deg_i N][pooled 16384] (one zero-fill) [offs N][dinv N][bsum 64]
  //         [bofs 64][rank E][csr E][yb N*128]
  int* W = (int*)d_ws;
  int*   deg_i  = W;
  float* pooled = (float*)(W + N);
  int*   offs   = W + N + N_GRAPHS * HIDDEN;
  float* dinv   = (float*)(offs + N);
  int*   bsum   = (int*)(dinv + N);
  int*   bofs   = bsum + 64;
  int*   rank   = bofs + 64;
  int*   csr    = rank + E;
  float* yb     = (float*)(csr + E);

  hipMemsetAsync(deg_i, 0, (size_t)(N + N_GRAPHS * HIDDEN) * sizeof(int), stream);

  const int tb = 256;
  k_deg<<<(E + tb - 1) / tb, tb, 0, stream>>>(edst, deg_i, rank, E);
  int nb = (N + 1023) / 1024;
  k_scan1<<<nb, 1024, 0, stream>>>(deg_i, offs, bsum, N);
  k_scan2<<<1, 64, 0, stream>>>(bsum, bofs, nb);
  k_scan3<<<(N + tb - 1) / tb, tb, 0, stream>>>(offs, bofs, deg_i, dinv, N);
  k_place<<<(E + tb - 1) / tb, tb, 0, stream>>>(esrc, edst, rank, offs, csr, E);
  k_agg<<<(N + 3) / 4, 256, 0, stream>>>(x, csr, offs, deg_i, dinv, yb, N);
  k_gemmpool<<<(N + GN - 1) / GN, 256, 0, stream>>>(yb, w1, b1, batch, pooled, N);
  k_head<<<N_GRAPHS, 256, 0, stream>>>(pooled, batch, N, w2, b2, w3, b3, out);
}